// Round 3
// baseline (180.463 us; speedup 1.0000x reference)
//
#include <hip/hip_runtime.h>
#include <hip/hip_bf16.h>

typedef float f32x4 __attribute__((ext_vector_type(4)));
typedef short s16x8 __attribute__((ext_vector_type(8)));

#define NROWS 8192
#define KDIM  1024
#define BM 256
#define BN 256
#define BK 32
#define NT (KDIM / BK)              // 32 K-tiles
#define NTILE2 (NROWS / BM)         // 32 tile-rows
#define NBLK2 (NTILE2 * (NTILE2 + 1) / 2)  // 528 upper-tri blocks

#define WAITV(n) asm volatile("s_waitcnt vmcnt(" #n ")" ::: "memory")

__device__ __forceinline__ void barrier_raw() {
    __builtin_amdgcn_sched_barrier(0);
    asm volatile("" ::: "memory");
    __builtin_amdgcn_s_barrier();
    asm volatile("" ::: "memory");
    __builtin_amdgcn_sched_barrier(0);
}

// round-to-nearest-even fp32 -> bf16 bits, also returns the rounded-back fp32 value
__device__ __forceinline__ unsigned short f2bf(float f, float& back) {
    union { float f; unsigned u; } a; a.f = f;
    unsigned r = a.u + 0x7fffu + ((a.u >> 16) & 1u);
    unsigned short b = (unsigned short)(r >> 16);
    union { unsigned u; float f; } c; c.u = ((unsigned)b) << 16;
    back = c.f;
    return b;
}

__device__ __forceinline__ void gl_lds16(const unsigned short* g, unsigned short* l) {
    __builtin_amdgcn_global_load_lds(
        (const __attribute__((address_space(1))) void*)g,
        (__attribute__((address_space(3))) void*)l, 16, 0, 0);
}

__global__ __launch_bounds__(256)
void prep_kernel(const float* __restrict__ in, unsigned short* __restrict__ abf,
                 float* __restrict__ sq) {
    const int row = blockIdx.x;
    const int t = threadIdx.x;
    const float4 v = reinterpret_cast<const float4*>(in + (size_t)row * KDIM)[t];
    float b0, b1, b2, b3;
    ushort4 u;
    u.x = f2bf(v.x, b0);
    u.y = f2bf(v.y, b1);
    u.z = f2bf(v.z, b2);
    u.w = f2bf(v.w, b3);
    reinterpret_cast<ushort4*>(abf + (size_t)row * KDIM)[t] = u;
    float s = b0 * b0 + b1 * b1 + b2 * b2 + b3 * b3;
    #pragma unroll
    for (int off = 32; off > 0; off >>= 1) s += __shfl_down(s, off);
    __shared__ float red[4];
    if ((t & 63) == 0) red[t >> 6] = s;
    __syncthreads();
    if (t == 0) sq[row] = red[0] + red[1] + red[2] + red[3];
}

// C = A*A^T upper-tri tiles, 256x256 tile, BK=32, 8 waves (2x4 of 128x64).
// 4-deep LDS ring, counted vmcnt (never 0 in main loop), raw s_barrier.
// LDS XOR-swizzle (chunk ^= row&3, 16B granularity): linear gl_lds dest +
// inverse-swizzled GLOBAL source + swizzled ds_read (both-sides, rule 21).
// Fused epilogue -sqrt(max(sqi+sqj-2c,0)); off-diag tiles mirror-written
// (reg index r contiguous in transposed address -> one float4 per fragment).
__global__ __launch_bounds__(512, 2)
void gemm_kernel(const unsigned short* __restrict__ A, const float* __restrict__ sq,
                 float* __restrict__ out) {
    __shared__ __attribute__((aligned(16))) unsigned short As[4][BM * BK / 2 * 2]; // 4 x 16KB
    __shared__ __attribute__((aligned(16))) unsigned short Bs[4][BN * BK / 2 * 2]; // 4 x 16KB

    // XCD-aware swizzle: 528 blocks, 528 % 8 == 0 -> bijective
    const int bid = blockIdx.x;
    const int cpx = NBLK2 >> 3;  // 66
    const int swz = (bid & 7) * cpx + (bid >> 3);

    // triangular decode: swz -> (bi, bj), bi <= bj; S(r) = r*(65-r)/2
    int bi = (int)((65.0f - sqrtf(65.0f * 65.0f - 8.0f * (float)swz)) * 0.5f);
    if (bi > NTILE2 - 1) bi = NTILE2 - 1;
    if (bi < 0) bi = 0;
    while ((bi + 1) * (65 - (bi + 1)) / 2 <= swz) ++bi;
    while (bi * (65 - bi) / 2 > swz) --bi;
    const int bj = bi + (swz - bi * (65 - bi) / 2);

    const int brow = bi * BM;
    const int bcol = bj * BN;

    const int t = threadIdx.x;       // 0..511
    const int lane = t & 63;
    const int wid = t >> 6;          // 0..7
    const int wr = wid >> 2;         // 0..1  -> rows wr*128..+127
    const int wc = wid & 3;          // 0..3  -> cols wc*64..+63

    // ---- staging addresses (pre-swizzled global source, linear LDS dest) ----
    // dest byte d = issue*8192 + t*16; logical row = d>>6, chunk=(d>>4)&3
    // physical LDS[d] must hold logical[d ^ ((row&3)<<4)] -> src chunk = chunk ^ (row&3)
    const int srow0 = t >> 2;                          // 0..127
    const int scol  = ((t & 3) ^ (srow0 & 3)) * 8;     // swizzled col (elements)
    const unsigned short* gA0 = A + (size_t)(brow + srow0) * KDIM + scol;
    const unsigned short* gA1 = A + (size_t)(brow + srow0 + 128) * KDIM + scol;
    const unsigned short* gB0 = A + (size_t)(bcol + srow0) * KDIM + scol;
    const unsigned short* gB1 = A + (size_t)(bcol + srow0 + 128) * KDIM + scol;

    auto stage = [&](int kt) {
        const int b = kt & 3;
        const int ko = kt * BK;
        gl_lds16(gA0 + ko, &As[b][0] + t * 8);
        gl_lds16(gA1 + ko, &As[b][0] + t * 8 + 4096);
        gl_lds16(gB0 + ko, &Bs[b][0] + t * 8);
        gl_lds16(gB1 + ko, &Bs[b][0] + t * 8 + 4096);
    };

    // ---- fragment read addresses (swizzled) ----
    const int fr = lane & 15;
    const int kq = lane >> 4;                   // 0..3
    const int kqs = (kq ^ (fr & 3)) * 8;        // swizzled k-chunk (elements)
    const int aoff = (wr * 128 + fr) * 32 + kqs;   // + m*512
    const int boff = (wc * 64 + fr) * 32 + kqs;    // + n*512

    f32x4 acc[8][4] = {};

    auto compute = [&](int b) {
        s16x8 af[8], bfr[4];
        const unsigned short* Ab = &As[b][0];
        const unsigned short* Bb = &Bs[b][0];
        #pragma unroll
        for (int m = 0; m < 8; ++m)
            af[m] = *reinterpret_cast<const s16x8*>(&Ab[aoff + m * 512]);
        #pragma unroll
        for (int n = 0; n < 4; ++n)
            bfr[n] = *reinterpret_cast<const s16x8*>(&Bb[boff + n * 512]);
        #pragma unroll
        for (int m = 0; m < 8; ++m)
            #pragma unroll
            for (int n = 0; n < 4; ++n)
                acc[m][n] = __builtin_amdgcn_mfma_f32_16x16x32_bf16(af[m], bfr[n], acc[m][n], 0, 0, 0);
    };

    // ---- prologue: fill 3 buffers ----
    stage(0); stage(1); stage(2);

    // ---- main loop: stage kt+3, wait vmcnt(12) (3 groups x 4 loads in flight) ----
    for (int kt = 0; kt < NT - 3; ++kt) {
        stage(kt + 3);
        WAITV(12);
        barrier_raw();
        compute(kt & 3);
        barrier_raw();
    }
    // ---- epilogue drain: 8 -> 4 -> 0 ----
    WAITV(8);
    barrier_raw();
    compute((NT - 3) & 3);
    barrier_raw();
    WAITV(4);
    barrier_raw();
    compute((NT - 2) & 3);
    barrier_raw();
    WAITV(0);
    barrier_raw();
    compute((NT - 1) & 3);

    // ---- epilogue: C/D layout col = lane&15 (fr), row = (lane>>4)*4 + reg ----
    const int q = lane >> 4;
    const int ib = brow + wr * 128 + q * 4;     // + m*16 + r
    const int jb = bcol + wc * 64 + fr;         // + n*16
    float sqj[4];
    #pragma unroll
    for (int n = 0; n < 4; ++n) sqj[n] = sq[jb + n * 16];

    const bool offdiag = (bi != bj);
    #pragma unroll
    for (int m = 0; m < 8; ++m) {
        #pragma unroll
        for (int n = 0; n < 4; ++n) {
            f32x4 tv;
            #pragma unroll
            for (int r = 0; r < 4; ++r) {
                const int i = ib + m * 16 + r;
                const float d2 = sq[i] + sqj[n] - 2.0f * acc[m][n][r];
                tv[r] = -sqrtf(fmaxf(d2, 0.0f));
            }
            #pragma unroll
            for (int r = 0; r < 4; ++r) {
                const int i = ib + m * 16 + r;
                out[(size_t)i * NROWS + (jb + n * 16)] = tv[r];
            }
            if (offdiag) {
                const size_t mrow = (size_t)(jb + n * 16) * NROWS + (ib + m * 16);
                *reinterpret_cast<float4*>(&out[mrow]) = *(float4*)&tv;
            }
        }
    }
}

extern "C" void kernel_launch(void* const* d_in, const int* in_sizes, int n_in,
                              void* d_out, int out_size, void* d_ws, size_t ws_size,
                              hipStream_t stream) {
    const float* feat = (const float*)d_in[0];
    float* out = (float*)d_out;
    unsigned short* abf = (unsigned short*)d_ws;                       // 16 MB bf16 copy
    float* sq = (float*)((char*)d_ws + (size_t)NROWS * KDIM * 2);      // 32 KB row sums

    prep_kernel<<<NROWS, 256, 0, stream>>>(feat, abf, sq);
    gemm_kernel<<<NBLK2, 512, 0, stream>>>(abf, sq, out);
}

// Round 4
// 147.635 us; speedup vs baseline: 1.2224x; 1.2224x over previous
//
#include <hip/hip_runtime.h>
#include <hip/hip_bf16.h>

typedef float f32x4 __attribute__((ext_vector_type(4)));
typedef short s16x8 __attribute__((ext_vector_type(8)));

#define NROWS 8192
#define KDIM  1024
#define BM 128
#define BN 128
#define BK 32
#define NT (KDIM / BK)                 // 32 K-tiles
#define NTILE (NROWS / BM)             // 64 tile-rows
#define NBLK (NTILE * (NTILE + 1) / 2) // 2080 upper-tri blocks

#define WAITV(n) asm volatile("s_waitcnt vmcnt(" #n ")" ::: "memory")
#define SCHED0 __builtin_amdgcn_sched_barrier(0)
#define FENCE asm volatile("" ::: "memory")
#define BAR do { FENCE; __builtin_amdgcn_s_barrier(); FENCE; } while (0)

// round-to-nearest-even fp32 -> bf16 bits, also returns the rounded-back fp32 value
__device__ __forceinline__ unsigned short f2bf(float f, float& back) {
    union { float f; unsigned u; } a; a.f = f;
    unsigned r = a.u + 0x7fffu + ((a.u >> 16) & 1u);
    unsigned short b = (unsigned short)(r >> 16);
    union { unsigned u; float f; } c; c.u = ((unsigned)b) << 16;
    back = c.f;
    return b;
}

__device__ __forceinline__ void gl_lds16(const unsigned short* g, unsigned short* l) {
    __builtin_amdgcn_global_load_lds(
        (const __attribute__((address_space(1))) void*)g,
        (__attribute__((address_space(3))) void*)l, 16, 0, 0);
}

__global__ __launch_bounds__(256)
void prep_kernel(const float* __restrict__ in, unsigned short* __restrict__ abf,
                 float* __restrict__ sq) {
    const int row = blockIdx.x;
    const int t = threadIdx.x;
    const float4 v = reinterpret_cast<const float4*>(in + (size_t)row * KDIM)[t];
    float b0, b1, b2, b3;
    ushort4 u;
    u.x = f2bf(v.x, b0);
    u.y = f2bf(v.y, b1);
    u.z = f2bf(v.z, b2);
    u.w = f2bf(v.w, b3);
    reinterpret_cast<ushort4*>(abf + (size_t)row * KDIM)[t] = u;
    float s = b0 * b0 + b1 * b1 + b2 * b2 + b3 * b3;
    #pragma unroll
    for (int off = 32; off > 0; off >>= 1) s += __shfl_down(s, off);
    __shared__ float red[4];
    if ((t & 63) == 0) red[t >> 6] = s;
    __syncthreads();
    if (t == 0) sq[row] = red[0] + red[1] + red[2] + red[3];
}

// C = A*A^T upper-tri tiles, 128x128 tile, BK=32, 4 waves (2x2 of 64x64).
// 3-deep LDS ring (48KB -> 3 blocks/CU): step kt stages K-tile kt+2, computes
// K-tile kt, then vmcnt(4) (kt+1's loads complete, kt+2's stay in flight) +
// ONE raw s_barrier. Loads span ~2 compute phases -> latency hidden; never
// drains vmcnt to 0 in the main loop (T3/T4 minimum form).
// Fused epilogue -sqrt(max(sqi+sqj-2c,0)); off-diag tiles mirror-written.
__global__ __launch_bounds__(256)
void gemm_kernel(const unsigned short* __restrict__ A, const float* __restrict__ sq,
                 float* __restrict__ out) {
    __shared__ __attribute__((aligned(16))) unsigned short As[3][BM * BK]; // 3 x 8KB
    __shared__ __attribute__((aligned(16))) unsigned short Bs[3][BN * BK]; // 3 x 8KB

    // XCD-aware swizzle: 2080 blocks, 2080 % 8 == 0 -> bijective
    const int bid = blockIdx.x;
    const int cpx = NBLK >> 3;  // 260
    const int swz = (bid & 7) * cpx + (bid >> 3);

    // triangular decode: swz -> (bi, bj), bi <= bj; tiles in rows < r: r*(129-r)/2
    int bi = (int)((129.0f - sqrtf(129.0f * 129.0f - 8.0f * (float)swz)) * 0.5f);
    if (bi > NTILE - 1) bi = NTILE - 1;
    if (bi < 0) bi = 0;
    while ((bi + 1) * (129 - (bi + 1)) / 2 <= swz) ++bi;
    while (bi * (129 - bi) / 2 > swz) --bi;
    const int bj = bi + (swz - bi * (129 - bi) / 2);

    const int brow = bi * BM;
    const int bcol = bj * BN;

    const int t = threadIdx.x;
    const int lane = t & 63;
    const int wid = t >> 6;
    const int wr = wid >> 1;   // 0..1
    const int wc = wid & 1;    // 0..1

    f32x4 acc[4][4] = {};

    // staging: 8192 B per tile, 256 threads x 16 B x 2 issues per matrix
    const int o1 = t * 16;
    const int o2 = o1 + 4096;
    const int r1 = o1 >> 6, c1 = (o1 >> 4) & 3;
    const int r2 = o2 >> 6, c2 = (o2 >> 4) & 3;

    const unsigned short* Ag1 = A + (size_t)(brow + r1) * KDIM + c1 * 8;
    const unsigned short* Ag2 = A + (size_t)(brow + r2) * KDIM + c2 * 8;
    const unsigned short* Bg1 = A + (size_t)(bcol + r1) * KDIM + c1 * 8;
    const unsigned short* Bg2 = A + (size_t)(bcol + r2) * KDIM + c2 * 8;

    auto stage = [&](int kt, int b) {
        const int ko = kt * BK;
        gl_lds16(Ag1 + ko, (unsigned short*)((char*)&As[b][0] + o1));
        gl_lds16(Ag2 + ko, (unsigned short*)((char*)&As[b][0] + o2));
        gl_lds16(Bg1 + ko, (unsigned short*)((char*)&Bs[b][0] + o1));
        gl_lds16(Bg2 + ko, (unsigned short*)((char*)&Bs[b][0] + o2));
    };

    const int kq = lane >> 4;            // 0..3 -> k-subblock of 8
    const int fr = lane & 15;
    const int arow = wr * 64 + fr;
    const int brw  = wc * 64 + fr;

    auto compute = [&](int b) {
        s16x8 af[4], bfr[4];
        const unsigned short* Ab = &As[b][0];
        const unsigned short* Bb = &Bs[b][0];
        #pragma unroll
        for (int m = 0; m < 4; ++m)
            af[m] = *reinterpret_cast<const s16x8*>(&Ab[(arow + m * 16) * BK + kq * 8]);
        #pragma unroll
        for (int n = 0; n < 4; ++n)
            bfr[n] = *reinterpret_cast<const s16x8*>(&Bb[(brw + n * 16) * BK + kq * 8]);
        #pragma unroll
        for (int m = 0; m < 4; ++m)
            #pragma unroll
            for (int n = 0; n < 4; ++n)
                acc[m][n] = __builtin_amdgcn_mfma_f32_16x16x32_bf16(af[m], bfr[n], acc[m][n], 0, 0, 0);
    };

    // prologue: KT0, KT1 in flight; wait KT0 (vmcnt(4): KT1's 4 loads stay out)
    stage(0, 0);
    stage(1, 1);
    WAITV(4);
    SCHED0;
    BAR;

    int bc = 0;  // buffer of current K-tile
    for (int kt = 0; kt < NT - 2; ++kt) {
        const int bs = (bc + 2 >= 3) ? bc - 1 : bc + 2;  // (bc+2)%3
        stage(kt + 2, bs);
        compute(bc);
        SCHED0;        // pin MFMAs before the wait so they hide load latency
        WAITV(4);      // KT kt+1 landed; KT kt+2 stays in flight
        SCHED0;
        BAR;
        bc = (bc + 1 == 3) ? 0 : bc + 1;
    }
    // kt = NT-2: data guaranteed by last loop iteration's vmcnt(4)+barrier
    compute(bc);
    SCHED0;
    WAITV(0);      // drain KT NT-1's loads
    SCHED0;
    BAR;
    bc = (bc + 1 == 3) ? 0 : bc + 1;
    compute(bc);   // kt = NT-1

    // epilogue: C/D layout col = lane&15 (fr), row = (lane>>4)*4 + reg [m89/m91]
    const int q = lane >> 4;
    const int ib = brow + wr * 64 + q * 4;
    const int jb = bcol + wc * 64 + fr;
    float sqj[4];
    #pragma unroll
    for (int n = 0; n < 4; ++n) sqj[n] = sq[jb + n * 16];

    const bool offdiag = (bi != bj);
    #pragma unroll
    for (int m = 0; m < 4; ++m) {
        #pragma unroll
        for (int n = 0; n < 4; ++n) {
            f32x4 tv;
            #pragma unroll
            for (int r = 0; r < 4; ++r) {
                const int i = ib + m * 16 + r;
                const float d2 = sq[i] + sqj[n] - 2.0f * acc[m][n][r];
                tv[r] = -sqrtf(fmaxf(d2, 0.0f));
            }
            #pragma unroll
            for (int r = 0; r < 4; ++r) {
                const int i = ib + m * 16 + r;
                out[(size_t)i * NROWS + (jb + n * 16)] = tv[r];
            }
            if (offdiag) {
                const size_t mrow = (size_t)(jb + n * 16) * NROWS + (ib + m * 16);
                *reinterpret_cast<float4*>(&out[mrow]) = *(float4*)&tv;
            }
        }
    }
}

extern "C" void kernel_launch(void* const* d_in, const int* in_sizes, int n_in,
                              void* d_out, int out_size, void* d_ws, size_t ws_size,
                              hipStream_t stream) {
    const float* feat = (const float*)d_in[0];
    float* out = (float*)d_out;
    unsigned short* abf = (unsigned short*)d_ws;                       // 16 MB bf16 copy
    float* sq = (float*)((char*)d_ws + (size_t)NROWS * KDIM * 2);      // 32 KB row sums

    prep_kernel<<<NROWS, 256, 0, stream>>>(feat, abf, sq);
    gemm_kernel<<<NBLK, 256, 0, stream>>>(abf, sq, out);
}